// Round 1
// baseline (1045.760 us; speedup 1.0000x reference)
//
#include <hip/hip_runtime.h>
#include <math.h>

// ---------------- problem constants ----------------
#define ED    1024
#define GH    1024
#define NLAY  3
#define NHEAD 8
#define HD    128
#define NNODE 2048
#define BQ    1024
#define CAP   192          // neighbor-list capacity (mean ~41, binomial std ~6.3)

// ---------------- workspace layout (float elements) ----------------
// X     [2048,1024]  GNN state; later reused: QH = X[0:1M], PH = X[1M:2M]
// WH    [2048,1024]  Wh (head-concat); later reused: LG
// HATT  [2048,1024]  attention out;   later reused: Q = [0:1M], P = [1M:2M]
// WG    [1024,1024]  transposed gatW[l]; later reused: NEG
// G     [2048,1024]  graph embeds
// S1,S2 [8,2048]
// ACC   [0]=lap sum  [1]=nce sum
// NCNT  2048 ints, NBR 2048*CAP ints
static const size_t OFF_X    = 0;
static const size_t OFF_WH   = 2097152;
static const size_t OFF_HATT = 4194304;
static const size_t OFF_WG   = 6291456;
static const size_t OFF_G    = 7340032;
static const size_t OFF_S1   = 9437184;
static const size_t OFF_S2   = 9453568;
static const size_t OFF_ACC  = 9469952;
static const size_t OFF_NCNT = 9469968;   // int*
static const size_t OFF_NBR  = 9472016;   // int*

// ---------------- reductions ----------------
__device__ __forceinline__ float waveSum(float v) {
#pragma unroll
  for (int off = 32; off; off >>= 1) v += __shfl_xor(v, off, 64);
  return v;
}
__device__ __forceinline__ float waveMax(float v) {
#pragma unroll
  for (int off = 32; off; off >>= 1) v = fmaxf(v, __shfl_xor(v, off, 64));
  return v;
}
__device__ __forceinline__ float blockSum(float v) {
  __shared__ float buf[4];
  int lane = threadIdx.x & 63, wid = threadIdx.x >> 6, nw = (blockDim.x + 63) >> 6;
  v = waveSum(v);
  __syncthreads();
  if (lane == 0) buf[wid] = v;
  __syncthreads();
  float r = buf[0];
  for (int i = 1; i < nw; ++i) r += buf[i];
  return r;
}
__device__ __forceinline__ float blockMax(float v) {
  __shared__ float buf[4];
  int lane = threadIdx.x & 63, wid = threadIdx.x >> 6, nw = (blockDim.x + 63) >> 6;
  v = waveMax(v);
  __syncthreads();
  if (lane == 0) buf[wid] = v;
  __syncthreads();
  float r = buf[0];
  for (int i = 1; i < nw; ++i) r = fmaxf(r, buf[i]);
  return r;
}

// ---------------- fp32 tiled GEMM: C = scale*(A@B) + bias ----------------
// A [M,K] rm, B [K,N] rm, C [M,N] rm. M%64==0, N%64==0, K%16==0.
#define BM 64
#define BN 64
#define BK 16
__global__ __launch_bounds__(256) void gemm_nn(
    const float* __restrict__ A, const float* __restrict__ B,
    float* __restrict__ C, const float* __restrict__ bias,
    int M, int N, int K, float scale) {
  __shared__ float As[BK][BM];
  __shared__ float Bs[BK][BN];
  int tid = threadIdx.x;
  int bm = blockIdx.y * BM, bn = blockIdx.x * BN;
  int arow = tid >> 2, acol = (tid & 3) << 2;    // A: 64 rows x 16 k
  int brow = tid >> 4, bcol = (tid & 15) << 2;   // B: 16 k x 64 cols
  int tx = tid & 15, ty = tid >> 4;
  float acc[4][4] = {};
  for (int k0 = 0; k0 < K; k0 += BK) {
    float4 av = *(const float4*)&A[(size_t)(bm + arow) * K + k0 + acol];
    float4 bv = *(const float4*)&B[(size_t)(k0 + brow) * N + bn + bcol];
    __syncthreads();
    As[acol + 0][arow] = av.x; As[acol + 1][arow] = av.y;
    As[acol + 2][arow] = av.z; As[acol + 3][arow] = av.w;
    *(float4*)&Bs[brow][bcol] = bv;
    __syncthreads();
#pragma unroll
    for (int k = 0; k < BK; ++k) {
      float ar[4], br[4];
      *(float4*)ar = *(const float4*)&As[k][ty << 2];
      *(float4*)br = *(const float4*)&Bs[k][tx << 2];
#pragma unroll
      for (int i = 0; i < 4; ++i)
#pragma unroll
        for (int j = 0; j < 4; ++j) acc[i][j] += ar[i] * br[j];
    }
  }
#pragma unroll
  for (int i = 0; i < 4; ++i) {
    int r = bm + (ty << 2) + i;
#pragma unroll
    for (int j = 0; j < 4; ++j) {
      int c = bn + (tx << 2) + j;
      float v = acc[i][j] * scale;
      if (bias) v += bias[c];
      C[(size_t)r * N + c] = v;
    }
  }
}

// C = scale * (A @ Bt^T);  A [M,K], Bt [N,K]
__global__ __launch_bounds__(256) void gemm_nt(
    const float* __restrict__ A, const float* __restrict__ Bt,
    float* __restrict__ C, int M, int N, int K, float scale) {
  __shared__ float As[BK][BM];
  __shared__ float Bs[BK][BN];
  int tid = threadIdx.x;
  int bm = blockIdx.y * BM, bn = blockIdx.x * BN;
  int arow = tid >> 2, acol = (tid & 3) << 2;
  int tx = tid & 15, ty = tid >> 4;
  float acc[4][4] = {};
  for (int k0 = 0; k0 < K; k0 += BK) {
    float4 av = *(const float4*)&A[(size_t)(bm + arow) * K + k0 + acol];
    float4 bv = *(const float4*)&Bt[(size_t)(bn + arow) * K + k0 + acol];
    __syncthreads();
    As[acol + 0][arow] = av.x; As[acol + 1][arow] = av.y;
    As[acol + 2][arow] = av.z; As[acol + 3][arow] = av.w;
    Bs[acol + 0][arow] = bv.x; Bs[acol + 1][arow] = bv.y;
    Bs[acol + 2][arow] = bv.z; Bs[acol + 3][arow] = bv.w;
    __syncthreads();
#pragma unroll
    for (int k = 0; k < BK; ++k) {
      float ar[4], br[4];
      *(float4*)ar = *(const float4*)&As[k][ty << 2];
      *(float4*)br = *(const float4*)&Bs[k][tx << 2];
#pragma unroll
      for (int i = 0; i < 4; ++i)
#pragma unroll
        for (int j = 0; j < 4; ++j) acc[i][j] += ar[i] * br[j];
    }
  }
#pragma unroll
  for (int i = 0; i < 4; ++i) {
    int r = bm + (ty << 2) + i;
#pragma unroll
    for (int j = 0; j < 4; ++j) {
      int c = bn + (tx << 2) + j;
      C[(size_t)r * N + c] = acc[i][j] * scale;
    }
  }
}

// ---------------- GNN helpers ----------------
// Wg[f, h*128+o] = gatW_l[h, f, o]
__global__ void gat_transpose(const float* __restrict__ gatW_l, float* __restrict__ Wg) {
  int idx = blockIdx.x * 256 + threadIdx.x;       // 1024*1024
  int f = idx >> 10, c = idx & 1023;
  int h = c >> 7, o = c & 127;
  Wg[idx] = gatW_l[(h << 17) + (f << 7) + o];
}

__global__ void build_nbr(const float* __restrict__ adj, int* __restrict__ nbr,
                          int* __restrict__ ncnt) {
  __shared__ int cnt;
  int n = blockIdx.x, tid = threadIdx.x;
  if (tid == 0) cnt = 0;
  __syncthreads();
  for (int c = tid; c < NNODE; c += 256) {
    if (adj[((size_t)n << 11) + c] > 0.f) {
      int p = atomicAdd(&cnt, 1);
      if (p < CAP) nbr[n * CAP + p] = c;
    }
  }
  __syncthreads();
  if (tid == 0) ncnt[n] = cnt < CAP ? cnt : CAP;
}

// s1[h,n] = sum_o WH[n, h*128+o]*a1l[h,o]  (and same for s2)
__global__ __launch_bounds__(128) void s1s2_kernel(
    const float* __restrict__ WH, const float* __restrict__ a1l,
    const float* __restrict__ a2l, float* __restrict__ S1, float* __restrict__ S2) {
  __shared__ float b1[2], b2[2];
  int h = blockIdx.x & 7, n = blockIdx.x >> 3;
  int o = threadIdx.x;
  float w = WH[((size_t)n << 10) + (h << 7) + o];
  float p1 = w * a1l[(h << 7) + o];
  float p2 = w * a2l[(h << 7) + o];
  p1 = waveSum(p1); p2 = waveSum(p2);
  int lane = o & 63, wid = o >> 6;
  if (lane == 0) { b1[wid] = p1; b2[wid] = p2; }
  __syncthreads();
  if (o == 0) {
    S1[(h << 11) + n] = b1[0] + b1[1];
    S2[(h << 11) + n] = b2[0] + b2[1];
  }
}

// fused masked softmax + PV per (head, node)
__global__ __launch_bounds__(128) void att_pv(
    const float* __restrict__ WH, const float* __restrict__ S1,
    const float* __restrict__ S2, const int* __restrict__ nbr,
    const int* __restrict__ ncnt, float* __restrict__ HATT) {
  __shared__ float ew[CAP];
  __shared__ int   mi[CAP];
  int h = blockIdx.x & 7, n = blockIdx.x >> 3;
  int tid = threadIdx.x;
  int cnt = ncnt[n];
  float s1v = S1[(h << 11) + n];
  for (int j = tid; j < cnt; j += 128) {
    int m = nbr[n * CAP + j];
    mi[j] = m;
    float e = s1v + S2[(h << 11) + m];
    ew[j] = e > 0.f ? e : 0.2f * e;           // leaky_relu(., 0.2)
  }
  __syncthreads();
  float lmax = -1e30f;
  for (int j = tid; j < cnt; j += 128) lmax = fmaxf(lmax, ew[j]);
  float emax = blockMax(lmax);
  float lsum = 0.f;
  for (int j = tid; j < cnt; j += 128) {
    float w = expf(ew[j] - emax);
    ew[j] = w;
    lsum += w;
  }
  float denom = blockSum(lsum);
  float inv = 1.f / denom;
  int o = tid;                                 // HD=128 output dims
  float acc = 0.f;
  for (int j = 0; j < cnt; ++j)
    acc += ew[j] * WH[((size_t)mi[j] << 10) + (h << 7) + o];
  HATT[((size_t)n << 10) + (h << 7) + o] = acc * inv;
}

// x += elu(layernorm(h; g,b))
__global__ __launch_bounds__(256) void ln_elu_res(
    const float* __restrict__ H, float* __restrict__ X,
    const float* __restrict__ g, const float* __restrict__ b) {
  int row = blockIdx.x, tid = threadIdx.x;
  float4 v = *(const float4*)&H[((size_t)row << 10) + (tid << 2)];
  float s = v.x + v.y + v.z + v.w;
  float sq = v.x * v.x + v.y * v.y + v.z * v.z + v.w * v.w;
  float mean = blockSum(s) * (1.f / 1024.f);
  float var = blockSum(sq) * (1.f / 1024.f) - mean * mean;
  float rstd = rsqrtf(fmaxf(var, 0.f) + 1e-5f);
  float vals[4] = {v.x, v.y, v.z, v.w};
  float4 xv = *(float4*)&X[((size_t)row << 10) + (tid << 2)];
  float xa[4] = {xv.x, xv.y, xv.z, xv.w};
#pragma unroll
  for (int i = 0; i < 4; ++i) {
    int c = (tid << 2) + i;
    float y = (vals[i] - mean) * rstd * g[c] + b[c];
    y = y > 0.f ? y : expm1f(y);               // elu
    xa[i] += y;
  }
  *(float4*)&X[((size_t)row << 10) + (tid << 2)] = make_float4(xa[0], xa[1], xa[2], xa[3]);
}

// in-place: x = gelu(layernorm(x; g,b))  (exact gelu)
__global__ __launch_bounds__(256) void ln_gelu(
    float* __restrict__ IO, const float* __restrict__ g, const float* __restrict__ b) {
  int row = blockIdx.x, tid = threadIdx.x;
  float4 v = *(float4*)&IO[((size_t)row << 10) + (tid << 2)];
  float s = v.x + v.y + v.z + v.w;
  float sq = v.x * v.x + v.y * v.y + v.z * v.z + v.w * v.w;
  float mean = blockSum(s) * (1.f / 1024.f);
  float var = blockSum(sq) * (1.f / 1024.f) - mean * mean;
  float rstd = rsqrtf(fmaxf(var, 0.f) + 1e-5f);
  float vals[4] = {v.x, v.y, v.z, v.w};
#pragma unroll
  for (int i = 0; i < 4; ++i) {
    int c = (tid << 2) + i;
    float y = (vals[i] - mean) * rstd * g[c] + b[c];
    vals[i] = 0.5f * y * (1.f + erff(y * 0.70710678118654752f));
  }
  *(float4*)&IO[((size_t)row << 10) + (tid << 2)] = make_float4(vals[0], vals[1], vals[2], vals[3]);
}

__global__ __launch_bounds__(256) void l2norm_k(float* __restrict__ Q) {
  int row = blockIdx.x, tid = threadIdx.x;
  float4 v = *(float4*)&Q[((size_t)row << 10) + (tid << 2)];
  float sq = v.x * v.x + v.y * v.y + v.z * v.z + v.w * v.w;
  float s = blockSum(sq);
  float inv = 1.f / fmaxf(sqrtf(s), 1e-12f);
  v.x *= inv; v.y *= inv; v.z *= inv; v.w *= inv;
  *(float4*)&Q[((size_t)row << 10) + (tid << 2)] = v;
}

// per-row logsumexp over [pos | neg_row] minus pos; accumulate into acc[1]
__global__ __launch_bounds__(256) void lse_kernel(const float* __restrict__ NEG,
                                                  float* __restrict__ acc) {
  int bq = blockIdx.x, tid = threadIdx.x;
  const float* row = NEG + ((size_t)bq << 10);
  float4 v = *(const float4*)&row[tid << 2];
  float lm = fmaxf(fmaxf(v.x, v.y), fmaxf(v.z, v.w));
  float m = blockMax(lm);                     // pos == row[bq] is in the row, so m is global max
  float ls = expf(v.x - m) + expf(v.y - m) + expf(v.z - m) + expf(v.w - m);
  float ssum = blockSum(ls);
  if (tid == 0) {
    float pos = row[bq];
    float loss = m + logf(ssum + expf(pos - m)) - pos;   // pos counted twice (concat)
    atomicAdd(acc + 1, loss);
  }
}

__global__ __launch_bounds__(256) void dot_reduce(const float* __restrict__ A,
                                                  const float* __restrict__ B,
                                                  float* __restrict__ acc, int n4) {
  int idx = blockIdx.x * blockDim.x + threadIdx.x;
  float s = 0.f;
  for (int i = idx; i < n4; i += gridDim.x * blockDim.x) {
    float4 a = ((const float4*)A)[i];
    float4 b = ((const float4*)B)[i];
    s += a.x * b.x + a.y * b.y + a.z * b.z + a.w * b.w;
  }
  s = blockSum(s);
  if (threadIdx.x == 0) atomicAdd(acc + 0, s);
}

__global__ void final_kernel(const float* __restrict__ acc, float* __restrict__ out) {
  float lap = acc[0] / 2048.f;
  float info = acc[1] / 1024.f;
  out[0] = info + 0.1f * lap;
  out[1] = info;
  out[2] = lap;
}

// ---------------- host launcher ----------------
extern "C" void kernel_launch(void* const* d_in, const int* in_sizes, int n_in,
                              void* d_out, int out_size, void* d_ws, size_t ws_size,
                              hipStream_t stream) {
  const float* query = (const float*)d_in[0];
  const float* docs  = (const float*)d_in[1];
  const float* nodes = (const float*)d_in[2];
  const float* adj   = (const float*)d_in[3];
  const float* lapl  = (const float*)d_in[4];
  const float* qW1 = (const float*)d_in[5],  *qb1 = (const float*)d_in[6];
  const float* qg  = (const float*)d_in[7],  *qbt = (const float*)d_in[8];
  const float* qW2 = (const float*)d_in[9],  *qb2 = (const float*)d_in[10];
  const float* dW1 = (const float*)d_in[11], *db1 = (const float*)d_in[12];
  const float* dg  = (const float*)d_in[13], *dbt = (const float*)d_in[14];
  const float* dW2 = (const float*)d_in[15], *db2 = (const float*)d_in[16];
  const float* gatW = (const float*)d_in[17];
  const float* a1   = (const float*)d_in[18];
  const float* a2   = (const float*)d_in[19];
  const float* ln_g = (const float*)d_in[20];
  const float* ln_b = (const float*)d_in[21];
  const float* poW  = (const float*)d_in[22];
  const float* pob  = (const float*)d_in[23];
  float* out = (float*)d_out;

  float* ws = (float*)d_ws;
  float* X    = ws + OFF_X;
  float* WH   = ws + OFF_WH;
  float* HATT = ws + OFF_HATT;
  float* WG   = ws + OFF_WG;
  float* G    = ws + OFF_G;
  float* S1   = ws + OFF_S1;
  float* S2   = ws + OFF_S2;
  float* ACC  = ws + OFF_ACC;
  int*   NCNT = (int*)(ws + OFF_NCNT);
  int*   NBR  = (int*)(ws + OFF_NBR);
  // reuse
  float* LG = WH;
  float* QH = X;
  float* PH = X + 1048576;
  float* Q  = HATT;
  float* P  = HATT + 1048576;
  float* NEG = WG;

  hipMemsetAsync(ACC, 0, 2 * sizeof(float), stream);
  build_nbr<<<NNODE, 256, 0, stream>>>(adj, NBR, NCNT);
  hipMemcpyAsync(X, nodes, (size_t)NNODE * GH * sizeof(float),
                 hipMemcpyDeviceToDevice, stream);

  for (int l = 0; l < NLAY; ++l) {
    gat_transpose<<<4096, 256, 0, stream>>>(gatW + (size_t)l * NHEAD * ED * HD, WG);
    gemm_nn<<<dim3(GH / BN, NNODE / BM), 256, 0, stream>>>(
        X, WG, WH, nullptr, NNODE, GH, ED, 1.f);
    s1s2_kernel<<<NNODE * NHEAD, 128, 0, stream>>>(
        WH, a1 + (size_t)l * NHEAD * HD, a2 + (size_t)l * NHEAD * HD, S1, S2);
    att_pv<<<NNODE * NHEAD, 128, 0, stream>>>(WH, S1, S2, NBR, NCNT, HATT);
    ln_elu_res<<<NNODE, 256, 0, stream>>>(HATT, X,
        ln_g + (size_t)l * GH, ln_b + (size_t)l * GH);
  }

  // graph_embeds + laplacian term
  gemm_nn<<<dim3(ED / BN, NNODE / BM), 256, 0, stream>>>(
      X, poW, G, pob, NNODE, ED, GH, 1.f);
  gemm_nn<<<dim3(ED / BN, NNODE / BM), 256, 0, stream>>>(
      lapl, G, LG, nullptr, NNODE, ED, NNODE, 1.f);
  dot_reduce<<<512, 256, 0, stream>>>(G, LG, ACC, NNODE * ED / 4);

  // query MLP
  gemm_nn<<<dim3(ED / BN, BQ / BM), 256, 0, stream>>>(
      query, qW1, QH, qb1, BQ, ED, ED, 1.f);
  ln_gelu<<<BQ, 256, 0, stream>>>(QH, qg, qbt);
  gemm_nn<<<dim3(ED / BN, BQ / BM), 256, 0, stream>>>(
      QH, qW2, Q, qb2, BQ, ED, ED, 1.f);
  l2norm_k<<<BQ, 256, 0, stream>>>(Q);

  // doc MLP
  gemm_nn<<<dim3(ED / BN, BQ / BM), 256, 0, stream>>>(
      docs, dW1, PH, db1, BQ, ED, ED, 1.f);
  ln_gelu<<<BQ, 256, 0, stream>>>(PH, dg, dbt);
  gemm_nn<<<dim3(ED / BN, BQ / BM), 256, 0, stream>>>(
      PH, dW2, P, db2, BQ, ED, ED, 1.f);
  l2norm_k<<<BQ, 256, 0, stream>>>(P);

  // similarities + InfoNCE
  gemm_nt<<<dim3(BQ / BN, BQ / BM), 256, 0, stream>>>(
      Q, P, NEG, BQ, BQ, ED, 20.f);               // 1/TEMP
  lse_kernel<<<BQ, 256, 0, stream>>>(NEG, ACC);

  final_kernel<<<1, 1, 0, stream>>>(ACC, out);
}

// Round 2
// 619.393 us; speedup vs baseline: 1.6884x; 1.6884x over previous
//
#include <hip/hip_runtime.h>
#include <math.h>

// ---------------- problem constants ----------------
#define ED    1024
#define GH    1024
#define NLAY  3
#define NHEAD 8
#define HD    128
#define NNODE 2048
#define BQ    1024
#define CAP   192

typedef unsigned short u16;
typedef __attribute__((ext_vector_type(8))) short short8;
typedef __attribute__((ext_vector_type(4))) float f32x4;

// ---------------- workspace layout (float units) ----------------
// S0 [0,2M):   X fp32        -> laplb bf16 -> QH/Qf fp32 [0:1M), PH/Pf [1M:2M)
// S1 [2M,4M):  WH fp32       -> LG fp32    -> Qb,Pb,QHb,PHb bf16 (0.5M each)
// S2 [4M,6M):  HATT fp32     -> G fp32     -> Qnb,Pnb bf16 + NEG fp32 [1M:2M)
// S3 [6M,6.5M): weight-transpose bf16 slot (WGb / poWt / qW1t / ...)
// S4 [6.5M,7.5M): Xb bf16    -> Gt bf16
// then S1v, S2v, ACC, NCNT, NBR
static const size_t OFF_S0  = 0;
static const size_t OFF_S1  = 2097152;
static const size_t OFF_S2  = 4194304;
static const size_t OFF_S3  = 6291456;
static const size_t OFF_S4  = 6815744;
static const size_t OFF_SV1 = 7864320;
static const size_t OFF_SV2 = 7880704;
static const size_t OFF_ACC = 7897088;
static const size_t OFF_NCNT= 7897096;   // int*
static const size_t OFF_NBR = 7899144;   // int*  (ends 8292360 floats = 33.2 MB)

// ---------------- helpers ----------------
__device__ __forceinline__ u16 f2bf(float f) {
  unsigned int u = __float_as_uint(f);
  unsigned int r = (u + 0x7fffu + ((u >> 16) & 1u)) >> 16;
  return (u16)r;
}

__device__ __forceinline__ void gload_lds16(const void* g, void* l) {
  __builtin_amdgcn_global_load_lds(
      (__attribute__((address_space(1))) void*)(g),
      (__attribute__((address_space(3))) void*)(l), 16, 0, 0);
}

__device__ __forceinline__ float waveSum(float v) {
#pragma unroll
  for (int off = 32; off; off >>= 1) v += __shfl_xor(v, off, 64);
  return v;
}
__device__ __forceinline__ float waveMax(float v) {
#pragma unroll
  for (int off = 32; off; off >>= 1) v = fmaxf(v, __shfl_xor(v, off, 64));
  return v;
}
__device__ __forceinline__ float blockSum(float v) {
  __shared__ float buf[4];
  int lane = threadIdx.x & 63, wid = threadIdx.x >> 6, nw = (blockDim.x + 63) >> 6;
  v = waveSum(v);
  __syncthreads();
  if (lane == 0) buf[wid] = v;
  __syncthreads();
  float r = buf[0];
  for (int i = 1; i < nw; ++i) r += buf[i];
  return r;
}
__device__ __forceinline__ float blockMax(float v) {
  __shared__ float buf[4];
  int lane = threadIdx.x & 63, wid = threadIdx.x >> 6, nw = (blockDim.x + 63) >> 6;
  v = waveMax(v);
  __syncthreads();
  if (lane == 0) buf[wid] = v;
  __syncthreads();
  float r = buf[0];
  for (int i = 1; i < nw; ++i) r = fmaxf(r, buf[i]);
  return r;
}

// ---------------- bf16 MFMA GEMM: C = scale*(A @ Bt^T) + bias ----------------
// A [M,K] bf16 row-major, Bt [N,K] bf16 row-major, C [M,N] fp32.
// M,N % 128 == 0, K % 32 == 0. m97 structure: 128x128 tile, BK=32,
// global_load_lds width-16 staging, swizzled so frag ds_read_b128 is 2-way (free).
#define TBM 128
#define TBN 128
#define TBK 32
__global__ __launch_bounds__(256) void gemm_bt(
    const u16* __restrict__ A, const u16* __restrict__ Bt,
    float* __restrict__ C, const float* __restrict__ bias,
    int M, int N, int K, float scale) {
  __shared__ u16 As[TBM][TBK];   // 8 KB
  __shared__ u16 Bs[TBN][TBK];   // 8 KB
  const int tid  = threadIdx.x;
  const int wave = tid >> 6, lane = tid & 63;
  const int bm = blockIdx.y * TBM, bn = blockIdx.x * TBN;

  // ---- staging addresses: wave stages rows [wave*32, wave*32+32) of As and Bs.
  // LDS gets base + lane*16: lane L -> lds row (L>>2), lds seg (L&3).
  // We choose the GLOBAL seg each lane fetches so that lds seg s holds global
  // seg s ^ f(row), f(row) = (row>>1)&3  -> frag reads spread over all 8
  // 4-bank clusters (2-way aliasing = free).
  int srow0 = wave * 32 + (lane >> 2);
  int srow1 = srow0 + 16;
  int sseg0 = (lane & 3) ^ ((srow0 >> 1) & 3);
  int sseg1 = (lane & 3) ^ ((srow1 >> 1) & 3);
  const u16* gA0 = A  + (size_t)(bm + srow0) * K + sseg0 * 8;
  const u16* gA1 = A  + (size_t)(bm + srow1) * K + sseg1 * 8;
  const u16* gB0 = Bt + (size_t)(bn + srow0) * K + sseg0 * 8;
  const u16* gB1 = Bt + (size_t)(bn + srow1) * K + sseg1 * 8;
  u16* lA0 = &As[wave * 32][0];
  u16* lA1 = &As[wave * 32 + 16][0];
  u16* lB0 = &Bs[wave * 32][0];
  u16* lB1 = &Bs[wave * 32 + 16][0];

  // ---- fragment read addresses (constant across K iters)
  const int wm = (wave >> 1) * 64, wn = (wave & 1) * 64;
  const int r16 = lane & 15, kgrp = lane >> 4;
  const u16* fa[4];
  const u16* fb[4];
#pragma unroll
  for (int i = 0; i < 4; ++i) {
    int row = wm + i * 16 + r16;
    fa[i] = &As[row][(kgrp ^ ((row >> 1) & 3)) * 8];
    int col = wn + i * 16 + r16;
    fb[i] = &Bs[col][(kgrp ^ ((col >> 1) & 3)) * 8];
  }

  f32x4 acc[4][4] = {};

  for (int k0 = 0; k0 < K; k0 += TBK) {
    __syncthreads();                 // protect LDS from previous iter's readers
    gload_lds16(gA0, lA0);
    gload_lds16(gA1, lA1);
    gload_lds16(gB0, lB0);
    gload_lds16(gB1, lB1);
    gA0 += TBK; gA1 += TBK; gB0 += TBK; gB1 += TBK;
    __syncthreads();                 // drains vmcnt before barrier
    short8 av[4], bv[4];
#pragma unroll
    for (int i = 0; i < 4; ++i) av[i] = *(const short8*)fa[i];
#pragma unroll
    for (int j = 0; j < 4; ++j) bv[j] = *(const short8*)fb[j];
#pragma unroll
    for (int i = 0; i < 4; ++i)
#pragma unroll
      for (int j = 0; j < 4; ++j)
        acc[i][j] = __builtin_amdgcn_mfma_f32_16x16x32_bf16(av[i], bv[j], acc[i][j], 0, 0, 0);
  }

  // ---- epilogue: C/D layout col=lane&15, row=(lane>>4)*4+reg (m89-verified)
#pragma unroll
  for (int j = 0; j < 4; ++j) {
    int col = bn + wn + j * 16 + r16;
    float bvv = bias ? bias[col] : 0.f;
#pragma unroll
    for (int i = 0; i < 4; ++i) {
      int row0 = bm + wm + i * 16 + kgrp * 4;
      float* cp = C + (size_t)row0 * N + col;
#pragma unroll
      for (int r = 0; r < 4; ++r)
        cp[(size_t)r * N] = acc[i][j][r] * scale + bvv;
    }
  }
}

// ---------------- conversion kernels ----------------
// fp32 -> bf16, same layout, n4 = elements/4
__global__ __launch_bounds__(256) void cvt_rows(const float* __restrict__ in,
                                                u16* __restrict__ out, int n4) {
  int i = blockIdx.x * 256 + threadIdx.x;
  if (i < n4) {
    float4 v = ((const float4*)in)[i];
    ushort4 o;
    o.x = f2bf(v.x); o.y = f2bf(v.y); o.z = f2bf(v.z); o.w = f2bf(v.w);
    ((ushort4*)out)[i] = o;
  }
}

// in fp32 [R][C] (batch stride inb) -> out bf16 [C][R] (batch stride outb)
__global__ __launch_bounds__(256) void cvt_transpose(
    const float* __restrict__ in, u16* __restrict__ out,
    int R, int C, long inb, long outb) {
  __shared__ float T[64][65];
  const float* ip = in + (size_t)blockIdx.z * inb;
  u16* op = out + (size_t)blockIdx.z * outb;
  int r0 = blockIdx.y * 64, c0 = blockIdx.x * 64;
  int t = threadIdx.x;
#pragma unroll
  for (int p = 0; p < 4; ++p) {
    int row = p * 16 + (t >> 4), col = (t & 15) * 4;
    float4 v = *(const float4*)&ip[(size_t)(r0 + row) * C + c0 + col];
    T[row][col] = v.x; T[row][col + 1] = v.y;
    T[row][col + 2] = v.z; T[row][col + 3] = v.w;
  }
  __syncthreads();
#pragma unroll
  for (int p = 0; p < 4; ++p) {
    int c = p * 16 + (t >> 4), r = (t & 15) * 4;
    ushort4 o;
    o.x = f2bf(T[r][c]); o.y = f2bf(T[r + 1][c]);
    o.z = f2bf(T[r + 2][c]); o.w = f2bf(T[r + 3][c]);
    *(ushort4*)&op[(size_t)(c0 + c) * R + r0 + r] = o;
  }
}

// ---------------- GNN helpers ----------------
__global__ void build_nbr(const float* __restrict__ adj, int* __restrict__ nbr,
                          int* __restrict__ ncnt) {
  __shared__ int cnt;
  int n = blockIdx.x, tid = threadIdx.x;
  if (tid == 0) cnt = 0;
  __syncthreads();
  for (int c = tid; c < NNODE; c += 256) {
    if (adj[((size_t)n << 11) + c] > 0.f) {
      int p = atomicAdd(&cnt, 1);
      if (p < CAP) nbr[n * CAP + p] = c;
    }
  }
  __syncthreads();
  if (tid == 0) ncnt[n] = cnt < CAP ? cnt : CAP;
}

__global__ __launch_bounds__(128) void s1s2_kernel(
    const float* __restrict__ WH, const float* __restrict__ a1l,
    const float* __restrict__ a2l, float* __restrict__ S1, float* __restrict__ S2) {
  __shared__ float b1[2], b2[2];
  int h = blockIdx.x & 7, n = blockIdx.x >> 3;
  int o = threadIdx.x;
  float w = WH[((size_t)n << 10) + (h << 7) + o];
  float p1 = w * a1l[(h << 7) + o];
  float p2 = w * a2l[(h << 7) + o];
  p1 = waveSum(p1); p2 = waveSum(p2);
  int lane = o & 63, wid = o >> 6;
  if (lane == 0) { b1[wid] = p1; b2[wid] = p2; }
  __syncthreads();
  if (o == 0) {
    S1[(h << 11) + n] = b1[0] + b1[1];
    S2[(h << 11) + n] = b2[0] + b2[1];
  }
}

__global__ __launch_bounds__(128) void att_pv(
    const float* __restrict__ WH, const float* __restrict__ S1,
    const float* __restrict__ S2, const int* __restrict__ nbr,
    const int* __restrict__ ncnt, float* __restrict__ HATT) {
  __shared__ float ew[CAP];
  __shared__ int   mi[CAP];
  int h = blockIdx.x & 7, n = blockIdx.x >> 3;
  int tid = threadIdx.x;
  int cnt = ncnt[n];
  float s1v = S1[(h << 11) + n];
  for (int j = tid; j < cnt; j += 128) {
    int m = nbr[n * CAP + j];
    mi[j] = m;
    float e = s1v + S2[(h << 11) + m];
    ew[j] = e > 0.f ? e : 0.2f * e;
  }
  __syncthreads();
  float lmax = -1e30f;
  for (int j = tid; j < cnt; j += 128) lmax = fmaxf(lmax, ew[j]);
  float emax = blockMax(lmax);
  float lsum = 0.f;
  for (int j = tid; j < cnt; j += 128) {
    float w = expf(ew[j] - emax);
    ew[j] = w;
    lsum += w;
  }
  float denom = blockSum(lsum);
  float inv = 1.f / denom;
  int o = tid;
  float acc = 0.f;
  for (int j = 0; j < cnt; ++j)
    acc += ew[j] * WH[((size_t)mi[j] << 10) + (h << 7) + o];
  HATT[((size_t)n << 10) + (h << 7) + o] = acc * inv;
}

// X += elu(layernorm(H)); also writes bf16 shadow Xb
__global__ __launch_bounds__(256) void ln_elu_res(
    const float* __restrict__ H, float* __restrict__ X, u16* __restrict__ Xb,
    const float* __restrict__ g, const float* __restrict__ b) {
  int row = blockIdx.x, tid = threadIdx.x;
  float4 v = *(const float4*)&H[((size_t)row << 10) + (tid << 2)];
  float s = v.x + v.y + v.z + v.w;
  float sq = v.x * v.x + v.y * v.y + v.z * v.z + v.w * v.w;
  float mean = blockSum(s) * (1.f / 1024.f);
  float var = blockSum(sq) * (1.f / 1024.f) - mean * mean;
  float rstd = rsqrtf(fmaxf(var, 0.f) + 1e-5f);
  float vals[4] = {v.x, v.y, v.z, v.w};
  float4 xv = *(float4*)&X[((size_t)row << 10) + (tid << 2)];
  float xa[4] = {xv.x, xv.y, xv.z, xv.w};
#pragma unroll
  for (int i = 0; i < 4; ++i) {
    int c = (tid << 2) + i;
    float y = (vals[i] - mean) * rstd * g[c] + b[c];
    y = y > 0.f ? y : expm1f(y);
    xa[i] += y;
  }
  *(float4*)&X[((size_t)row << 10) + (tid << 2)] = make_float4(xa[0], xa[1], xa[2], xa[3]);
  ushort4 o;
  o.x = f2bf(xa[0]); o.y = f2bf(xa[1]); o.z = f2bf(xa[2]); o.w = f2bf(xa[3]);
  *(ushort4*)&Xb[((size_t)row << 10) + (tid << 2)] = o;
}

// OUT(bf16) = gelu(layernorm(IN))
__global__ __launch_bounds__(256) void ln_gelu(
    const float* __restrict__ IN, u16* __restrict__ OUT,
    const float* __restrict__ g, const float* __restrict__ b) {
  int row = blockIdx.x, tid = threadIdx.x;
  float4 v = *(const float4*)&IN[((size_t)row << 10) + (tid << 2)];
  float s = v.x + v.y + v.z + v.w;
  float sq = v.x * v.x + v.y * v.y + v.z * v.z + v.w * v.w;
  float mean = blockSum(s) * (1.f / 1024.f);
  float var = blockSum(sq) * (1.f / 1024.f) - mean * mean;
  float rstd = rsqrtf(fmaxf(var, 0.f) + 1e-5f);
  float vals[4] = {v.x, v.y, v.z, v.w};
  ushort4 o;
  u16* oa = (u16*)&o;
#pragma unroll
  for (int i = 0; i < 4; ++i) {
    int c = (tid << 2) + i;
    float y = (vals[i] - mean) * rstd * g[c] + b[c];
    y = 0.5f * y * (1.f + erff(y * 0.70710678118654752f));
    oa[i] = f2bf(y);
  }
  *(ushort4*)&OUT[((size_t)row << 10) + (tid << 2)] = o;
}

// OUT(bf16) = l2normalize(IN)
__global__ __launch_bounds__(256) void l2norm_k(const float* __restrict__ IN,
                                                u16* __restrict__ OUT) {
  int row = blockIdx.x, tid = threadIdx.x;
  float4 v = *(const float4*)&IN[((size_t)row << 10) + (tid << 2)];
  float sq = v.x * v.x + v.y * v.y + v.z * v.z + v.w * v.w;
  float s = blockSum(sq);
  float inv = 1.f / fmaxf(sqrtf(s), 1e-12f);
  ushort4 o;
  o.x = f2bf(v.x * inv); o.y = f2bf(v.y * inv);
  o.z = f2bf(v.z * inv); o.w = f2bf(v.w * inv);
  *(ushort4*)&OUT[((size_t)row << 10) + (tid << 2)] = o;
}

__global__ __launch_bounds__(256) void lse_kernel(const float* __restrict__ NEG,
                                                  float* __restrict__ acc) {
  int bq = blockIdx.x, tid = threadIdx.x;
  const float* row = NEG + ((size_t)bq << 10);
  float4 v = *(const float4*)&row[tid << 2];
  float lm = fmaxf(fmaxf(v.x, v.y), fmaxf(v.z, v.w));
  float m = blockMax(lm);
  float ls = expf(v.x - m) + expf(v.y - m) + expf(v.z - m) + expf(v.w - m);
  float ssum = blockSum(ls);
  if (tid == 0) {
    float pos = row[bq];
    float loss = m + logf(ssum + expf(pos - m)) - pos;
    atomicAdd(acc + 1, loss);
  }
}

__global__ __launch_bounds__(256) void dot_reduce(const float* __restrict__ A,
                                                  const float* __restrict__ B,
                                                  float* __restrict__ acc, int n4) {
  int idx = blockIdx.x * blockDim.x + threadIdx.x;
  float s = 0.f;
  for (int i = idx; i < n4; i += gridDim.x * blockDim.x) {
    float4 a = ((const float4*)A)[i];
    float4 b = ((const float4*)B)[i];
    s += a.x * b.x + a.y * b.y + a.z * b.z + a.w * b.w;
  }
  s = blockSum(s);
  if (threadIdx.x == 0) atomicAdd(acc + 0, s);
}

__global__ void final_kernel(const float* __restrict__ acc, float* __restrict__ out) {
  float lap = acc[0] / 2048.f;
  float info = acc[1] / 1024.f;
  out[0] = info + 0.1f * lap;
  out[1] = info;
  out[2] = lap;
}

// ---------------- host launcher ----------------
extern "C" void kernel_launch(void* const* d_in, const int* in_sizes, int n_in,
                              void* d_out, int out_size, void* d_ws, size_t ws_size,
                              hipStream_t stream) {
  const float* query = (const float*)d_in[0];
  const float* docs  = (const float*)d_in[1];
  const float* nodes = (const float*)d_in[2];
  const float* adj   = (const float*)d_in[3];
  const float* lapl  = (const float*)d_in[4];
  const float* qW1 = (const float*)d_in[5],  *qb1 = (const float*)d_in[6];
  const float* qg  = (const float*)d_in[7],  *qbt = (const float*)d_in[8];
  const float* qW2 = (const float*)d_in[9],  *qb2 = (const float*)d_in[10];
  const float* dW1 = (const float*)d_in[11], *db1 = (const float*)d_in[12];
  const float* dg  = (const float*)d_in[13], *dbt = (const float*)d_in[14];
  const float* dW2 = (const float*)d_in[15], *db2 = (const float*)d_in[16];
  const float* gatW = (const float*)d_in[17];
  const float* a1   = (const float*)d_in[18];
  const float* a2   = (const float*)d_in[19];
  const float* ln_g = (const float*)d_in[20];
  const float* ln_b = (const float*)d_in[21];
  const float* poW  = (const float*)d_in[22];
  const float* pob  = (const float*)d_in[23];
  float* out = (float*)d_out;

  float* ws = (float*)d_ws;
  float* S0 = ws + OFF_S0;
  float* S1s = ws + OFF_S1;
  float* S2s = ws + OFF_S2;
  float* S3 = ws + OFF_S3;
  float* S4 = ws + OFF_S4;
  float* S1v = ws + OFF_SV1;
  float* S2v = ws + OFF_SV2;
  float* ACC = ws + OFF_ACC;
  int* NCNT = (int*)(ws + OFF_NCNT);
  int* NBR  = (int*)(ws + OFF_NBR);

  // aliases
  float* X    = S0;
  u16*   laplb= (u16*)S0;
  float* QH   = S0;                  // [1024,1024] fp32 (also Qf)
  float* PH   = S0 + 1048576;        //              (also Pf)
  float* WH   = S1s;
  float* LG   = S1s;
  u16*   Qb   = (u16*)S1s;
  u16*   Pb   = (u16*)(S1s + 524288);
  u16*   QHb  = (u16*)(S1s + 1048576);
  u16*   PHb  = (u16*)(S1s + 1572864);
  float* HATT = S2s;
  float* G    = S2s;
  u16*   Qnb  = (u16*)S2s;
  u16*   Pnb  = (u16*)(S2s + 524288);
  float* NEG  = S2s + 1048576;
  u16*   WGb  = (u16*)S3;            // weight transpose slot [1024][K]
  u16*   Xb   = (u16*)S4;
  u16*   Gt   = (u16*)S4;

  hipMemsetAsync(ACC, 0, 2 * sizeof(float), stream);
  build_nbr<<<NNODE, 256, 0, stream>>>(adj, NBR, NCNT);
  hipMemcpyAsync(X, nodes, (size_t)NNODE * GH * sizeof(float),
                 hipMemcpyDeviceToDevice, stream);
  cvt_rows<<<2048, 256, 0, stream>>>(nodes, Xb, NNODE * ED / 4);

  for (int l = 0; l < NLAY; ++l) {
    // WGb[h*128+o][f] = gatW[l][h][f][o]
    cvt_transpose<<<dim3(2, 16, 8), 256, 0, stream>>>(
        gatW + (size_t)l * NHEAD * ED * HD, WGb, ED, HD, (long)ED * HD, (long)HD * ED);
    gemm_bt<<<dim3(GH / TBN, NNODE / TBM), 256, 0, stream>>>(
        Xb, WGb, WH, nullptr, NNODE, GH, ED, 1.f);
    s1s2_kernel<<<NNODE * NHEAD, 128, 0, stream>>>(
        WH, a1 + (size_t)l * NHEAD * HD, a2 + (size_t)l * NHEAD * HD, S1v, S2v);
    att_pv<<<NNODE * NHEAD, 128, 0, stream>>>(WH, S1v, S2v, NBR, NCNT, HATT);
    ln_elu_res<<<NNODE, 256, 0, stream>>>(HATT, X, Xb,
        ln_g + (size_t)l * GH, ln_b + (size_t)l * GH);
  }

  // graph embeds + laplacian term
  cvt_transpose<<<dim3(16, 16, 1), 256, 0, stream>>>(poW, WGb, GH, ED, 0, 0);
  gemm_bt<<<dim3(ED / TBN, NNODE / TBM), 256, 0, stream>>>(
      Xb, WGb, G, pob, NNODE, ED, GH, 1.f);
  cvt_transpose<<<dim3(16, 32, 1), 256, 0, stream>>>(G, Gt, NNODE, ED, 0, 0);
  cvt_rows<<<4096, 256, 0, stream>>>(lapl, laplb, NNODE * NNODE / 4);
  gemm_bt<<<dim3(ED / TBN, NNODE / TBM), 256, 0, stream>>>(
      laplb, Gt, LG, nullptr, NNODE, ED, NNODE, 1.f);
  dot_reduce<<<512, 256, 0, stream>>>(G, LG, ACC, NNODE * ED / 4);

  // query MLP
  cvt_rows<<<1024, 256, 0, stream>>>(query, Qb, BQ * ED / 4);
  cvt_rows<<<1024, 256, 0, stream>>>(docs, Pb, BQ * ED / 4);
  cvt_transpose<<<dim3(16, 16, 1), 256, 0, stream>>>(qW1, WGb, ED, ED, 0, 0);
  gemm_bt<<<dim3(ED / TBN, BQ / TBM), 256, 0, stream>>>(
      Qb, WGb, QH, qb1, BQ, ED, ED, 1.f);
  ln_gelu<<<BQ, 256, 0, stream>>>(QH, QHb, qg, qbt);
  cvt_transpose<<<dim3(16, 16, 1), 256, 0, stream>>>(qW2, WGb, ED, ED, 0, 0);
  gemm_bt<<<dim3(ED / TBN, BQ / TBM), 256, 0, stream>>>(
      QHb, WGb, QH, qb2, BQ, ED, ED, 1.f);
  l2norm_k<<<BQ, 256, 0, stream>>>(QH, Qnb);

  // doc MLP
  cvt_transpose<<<dim3(16, 16, 1), 256, 0, stream>>>(dW1, WGb, ED, ED, 0, 0);
  gemm_bt<<<dim3(ED / TBN, BQ / TBM), 256, 0, stream>>>(
      Pb, WGb, PH, db1, BQ, ED, ED, 1.f);
  ln_gelu<<<BQ, 256, 0, stream>>>(PH, PHb, dg, dbt);
  cvt_transpose<<<dim3(16, 16, 1), 256, 0, stream>>>(dW2, WGb, ED, ED, 0, 0);
  gemm_bt<<<dim3(ED / TBN, BQ / TBM), 256, 0, stream>>>(
      PHb, WGb, PH, db2, BQ, ED, ED, 1.f);
  l2norm_k<<<BQ, 256, 0, stream>>>(PH, Pnb);

  // similarities + InfoNCE
  gemm_bt<<<dim3(BQ / TBN, BQ / TBM), 256, 0, stream>>>(
      Qnb, Pnb, NEG, nullptr, BQ, BQ, ED, 20.f);
  lse_kernel<<<BQ, 256, 0, stream>>>(NEG, ACC);

  final_kernel<<<1, 1, 0, stream>>>(ACC, out);
}